// Round 13
// baseline (143.339 us; speedup 1.0000x reference)
//
#include <hip/hip_runtime.h>
#include <hip/hip_bf16.h>
#include <math.h>

#define BATCH 8
#define CIN   384
#define HEADS 12
#define HGT   56
#define WID   56
#define HW    3136                 // 56*56
#define NPIX  (BATCH*HW)           // 25088
#define NVAL  384
#define NATT_W 1152                // attn2 width: head*96 + p*10 + q (consumer-major)
#define KSTEPS (CIN/32)            // 12
#define MB_TOT 196                 // m-tiles (NPIX/128)
#define NQKV  1536                 // wcat rows: 384 + 12*96

typedef __bf16 bf16x8 __attribute__((ext_vector_type(8)));
typedef __bf16 bf16x4 __attribute__((ext_vector_type(4)));
typedef float f32x4 __attribute__((ext_vector_type(4)));
typedef uint32_t u32x4 __attribute__((ext_vector_type(4)));
typedef __hip_bfloat16 hbf16;

__device__ __forceinline__ void gload_lds16(const void* g, void* l) {
  __builtin_amdgcn_global_load_lds(
      (const __attribute__((address_space(1))) void*)g,
      (__attribute__((address_space(3))) void*)l, 16, 0, 0);
}

// ---------------------------------------------------------------------------
// prep_all (unchanged): xb transpose-convert; wcat/bcat (Wv rows 0..383,
// Wa row 384+head*96+p*10+q); wpb convert.
// ---------------------------------------------------------------------------
#define NB_CONVX 9408
#define NB_WQKV  2304
#define NB_WP    576
__global__ __launch_bounds__(256) void prep_all(
    const float* __restrict__ x,
    const float* __restrict__ Wv, const float* __restrict__ Wa,
    const float* __restrict__ ba, const float* __restrict__ Wp,
    hbf16* __restrict__ xb, hbf16* __restrict__ wcat,
    float* __restrict__ bcat, hbf16* __restrict__ wpb)
{
  const int bid = blockIdx.x;
  const int tid = threadIdx.x;
  if (bid < NB_CONVX) {
    __shared__ float s[32][33];
    const int xt = bid % 98;
    const int yt = (bid / 98) % 12;
    const int b  = bid / (98 * 12);
    const int hw0 = xt * 32, c0 = yt * 32;
    const int tx = tid & 31, ty = tid >> 5;
    #pragma unroll
    for (int i = 0; i < 4; i++) {
      int c = c0 + ty + i * 8;
      s[ty + i * 8][tx] = x[((size_t)b * CIN + c) * HW + hw0 + tx];
    }
    __syncthreads();
    #pragma unroll
    for (int i = 0; i < 4; i++) {
      int hw = hw0 + ty + i * 8;
      xb[((size_t)b * HW + hw) * CIN + c0 + tx] =
          __float2bfloat16(s[tx][ty + i * 8]);
    }
  } else if (bid < NB_CONVX + NB_WQKV) {
    const int i = (bid - NB_CONVX) * 256 + tid;
    if (i < NQKV * CIN) {
      int n = i / CIN, k = i % CIN;
      float v = 0.f;
      if (n < NVAL) {
        v = Wv[(size_t)n * CIN + k];
      } else {
        int a = n - NVAL;                 // 0..1151
        int head = a / 96, r = a % 96, p = r / 10, q = r % 10;
        if (p < 9 && q < 9)
          v = Wa[(size_t)(head * 81 + p * 9 + q) * CIN + k];
      }
      wcat[i] = __float2bfloat16(v);
    }
    if (i < NQKV) {
      float bv = 0.f;
      if (i >= NVAL) {
        int a = i - NVAL;
        int head = a / 96, r = a % 96, p = r / 10, q = r % 10;
        if (p < 9 && q < 9) bv = ba[head * 81 + p * 9 + q];
      }
      bcat[i] = bv;
    }
  } else {
    const int i = (bid - NB_CONVX - NB_WQKV) * 256 + tid;
    if (i < CIN * CIN) wpb[i] = __float2bfloat16(Wp[i]);
  }
}

// ---------------------------------------------------------------------------
// gemm_fused (vproj MODE 0 / out-proj MODE 1): 128x128 tile, BK=32, 4 waves.
// Chunked-XCD 1-D grid: xcd = wgid&7 owns m-tiles [xcd*25, xcd*25+25),
// n-fastest within -> m-tile L2 reuse AND consecutive m-tiles same XCD.
// Grid = 8*25*3 = 600 blocks; mb>=196 blocks exit.
// ---------------------------------------------------------------------------
template<int MODE>
__global__ __launch_bounds__(256, 4) void gemm_fused(
    const hbf16* __restrict__ A_,
    const hbf16* __restrict__ Bt_,
    const float* __restrict__ bias,
    hbf16* __restrict__ ovp,      // MODE 0: vproj
    float* __restrict__ oput)     // MODE 1: out [B, 384, HW]
{
  const int xcd = blockIdx.x & 7;
  const int idx = blockIdx.x >> 3;
  const int mb = xcd * 25 + idx / 3;
  const int nb = idx % 3;
  if (mb >= MB_TOT) return;

  __shared__ __align__(16) char smem[33280];
  const __bf16* A  = (const __bf16*)A_;
  const __bf16* Bt = (const __bf16*)Bt_;

  const int tid  = threadIdx.x;
  const int wave = tid >> 6, lane = tid & 63;
  const int wr = wave >> 1, wc = wave & 1;
  const int l16 = lane & 15, kg = lane >> 4;
  const int m0 = mb * 128, n0 = nb * 128;

  float* biasLds = (float*)(smem + 32768);
  if (tid < 128) biasLds[tid] = bias[n0 + tid];

  const int srow = tid >> 2;
  const int skb  = (tid & 3) * 16;

  f32x4 acc[4][4] = {};

  auto stage = [&](int k0, int buf) {
    const char* gA = (const char*)(A  + (size_t)m0 * CIN + k0);
    const char* gB = (const char*)(Bt + (size_t)n0 * CIN + k0);
    char* lA = smem + buf * 16384;
    char* lB = smem + buf * 16384 + 8192;
    #pragma unroll
    for (int p = 0; p < 2; p++) {
      int row = p * 64 + srow;
      gload_lds16(gA + (size_t)row * (CIN * 2) + skb, lA + p * 4096 + wave * 1024);
      gload_lds16(gB + (size_t)row * (CIN * 2) + skb, lB + p * 4096 + wave * 1024);
    }
  };

  stage(0, 0);
  __syncthreads();

  for (int t = 0; t < KSTEPS; ++t) {
    const int buf = t & 1;
    if (t + 1 < KSTEPS) stage((t + 1) * 32, buf ^ 1);

    const __bf16* As = (const __bf16*)(smem + buf * 16384);
    const __bf16* Bs = (const __bf16*)(smem + buf * 16384 + 8192);
    bf16x8 af[4], bfr[4];
    #pragma unroll
    for (int mi = 0; mi < 4; mi++)
      af[mi] = *(const bf16x8*)(As + (wr * 64 + mi * 16 + l16) * 32 + kg * 8);
    #pragma unroll
    for (int ni = 0; ni < 4; ni++)
      bfr[ni] = *(const bf16x8*)(Bs + (wc * 64 + ni * 16 + l16) * 32 + kg * 8);
    #pragma unroll
    for (int mi = 0; mi < 4; mi++)
      #pragma unroll
      for (int ni = 0; ni < 4; ni++) {
        if (MODE == 0)
          acc[ni][mi] = __builtin_amdgcn_mfma_f32_16x16x32_bf16(
              bfr[ni], af[mi], acc[ni][mi], 0, 0, 0);
        else
          acc[mi][ni] = __builtin_amdgcn_mfma_f32_16x16x32_bf16(
              af[mi], bfr[ni], acc[mi][ni], 0, 0, 0);
      }
    __syncthreads();
  }

  if (MODE == 0) {
    __bf16* epi = (__bf16*)smem;
    #pragma unroll
    for (int ni = 0; ni < 4; ni++) {
      #pragma unroll
      for (int mi = 0; mi < 4; mi++) {
        const int m  = wr * 64 + mi * 16 + l16;
        const int nb2 = wc * 64 + ni * 16 + kg * 4;
        bf16x4 v4;
        #pragma unroll
        for (int r = 0; r < 4; r++)
          v4[r] = (__bf16)__float2bfloat16(acc[ni][mi][r] + biasLds[nb2 + r]);
        *(bf16x4*)(epi + m * 128 + (nb2 ^ ((m & 7) << 3))) = v4;
      }
    }
    __syncthreads();
    #pragma unroll
    for (int q = 0; q < 8; q++) {
      const int cid = q * 256 + tid;
      const int m = cid >> 4, nc = cid & 15;
      const int nloc = nc * 8;
      bf16x8 v = *(const bf16x8*)(epi + m * 128 + (nloc ^ ((m & 7) << 3)));
      *(bf16x8*)(ovp + (size_t)(m0 + m) * NVAL + n0 + nloc) = v;
    }
  } else {
    float* epi = (float*)smem;
    #pragma unroll
    for (int p = 0; p < 2; p++) {
      if (p) __syncthreads();
      if (wr == p) {
        #pragma unroll
        for (int mi = 0; mi < 4; mi++) {
          #pragma unroll
          for (int ni = 0; ni < 4; ni++) {
            const int n  = wc * 64 + ni * 16 + l16;
            const int ml = mi * 16 + kg * 4;
            f32x4 v;
            #pragma unroll
            for (int r = 0; r < 4; r++) v[r] = acc[mi][ni][r] + biasLds[n];
            *(f32x4*)(epi + n * 64 + (ml ^ ((n & 7) << 2))) = v;
          }
        }
      }
      __syncthreads();
      #pragma unroll
      for (int q = 0; q < 8; q++) {
        const int cid = q * 256 + tid;
        const int n = cid >> 4, mc = cid & 15;
        const int ml = mc * 4;
        f32x4 v = *(const f32x4*)(epi + n * 64 + (ml ^ ((n & 7) << 2)));
        const int mg = m0 + p * 64 + ml;
        const int b = mg / HW, hw = mg % HW;
        *(f32x4*)(oput + ((size_t)b * NVAL + n0 + n) * HW + hw) = v;
      }
    }
  }
}

// ---------------------------------------------------------------------------
// gemm_attn: 128(m) x 96(n = ONE head) tile, BK=32, 4 waves (2x2 of 64x48).
// Epilogue: LDS-transpose -> per (pixel m, p-row) softmax in-register ->
// store 10 bf16 probs CONSUMER-major: attn2[center+(i-1,j-1)][head*96+p*10].
// (center,p)->consumer is bijective; rows with OOB consumer are dropped;
// rows with OOB center are never written (fold masks exactly those).
// Chunked-XCD grid: 8*25*12 = 2400 blocks.
// ---------------------------------------------------------------------------
__global__ __launch_bounds__(256, 4) void gemm_attn(
    const hbf16* __restrict__ A_,
    const hbf16* __restrict__ Bt_,
    const float* __restrict__ bias,
    hbf16* __restrict__ attn2)
{
  const int xcd = blockIdx.x & 7;
  const int idx = blockIdx.x >> 3;
  const int mb = xcd * 25 + idx / 12;
  const int h  = idx % 12;
  if (mb >= MB_TOT) return;

  __shared__ __align__(16) char smem[33280];
  const __bf16* A  = (const __bf16*)A_;
  const __bf16* Bt = (const __bf16*)Bt_;

  const int tid  = threadIdx.x;
  const int wave = tid >> 6, lane = tid & 63;
  const int wr = wave >> 1, wc = wave & 1;
  const int l16 = lane & 15, kg = lane >> 4;
  const int m0 = mb * 128;
  const int n0w = NVAL + h * 96;          // wcat row base for this head

  float* biasLds = (float*)(smem + 32768);
  if (tid < 96) biasLds[tid] = bias[n0w + tid];

  const int srow = tid >> 2;
  const int skb  = (tid & 3) * 16;

  f32x4 acc[3][4] = {};

  auto stage = [&](int k0, int buf) {
    const char* gA = (const char*)(A  + (size_t)m0 * CIN + k0);
    const char* gB = (const char*)(Bt + (size_t)n0w * CIN + k0);
    char* lA = smem + buf * 16384;
    char* lB = smem + buf * 16384 + 8192;
    #pragma unroll
    for (int p = 0; p < 2; p++) {
      int row = p * 64 + srow;
      gload_lds16(gA + (size_t)row * (CIN * 2) + skb, lA + p * 4096 + wave * 1024);
      if (row < 96)   // wave-uniform: rows 96..127 (waves 2,3 of p=1) skipped
        gload_lds16(gB + (size_t)row * (CIN * 2) + skb, lB + p * 4096 + wave * 1024);
    }
  };

  stage(0, 0);
  __syncthreads();

  for (int t = 0; t < KSTEPS; ++t) {
    const int buf = t & 1;
    if (t + 1 < KSTEPS) stage((t + 1) * 32, buf ^ 1);

    const __bf16* As = (const __bf16*)(smem + buf * 16384);
    const __bf16* Bs = (const __bf16*)(smem + buf * 16384 + 8192);
    bf16x8 af[4], bfr[3];
    #pragma unroll
    for (int mi = 0; mi < 4; mi++)
      af[mi] = *(const bf16x8*)(As + (wr * 64 + mi * 16 + l16) * 32 + kg * 8);
    #pragma unroll
    for (int ni = 0; ni < 3; ni++)
      bfr[ni] = *(const bf16x8*)(Bs + (wc * 48 + ni * 16 + l16) * 32 + kg * 8);
    #pragma unroll
    for (int mi = 0; mi < 4; mi++)
      #pragma unroll
      for (int ni = 0; ni < 3; ni++)
        acc[ni][mi] = __builtin_amdgcn_mfma_f32_16x16x32_bf16(
            bfr[ni], af[mi], acc[ni][mi], 0, 0, 0);   // lane=m, regs=n
    __syncthreads();
  }

  // ---- epilogue: epi[m 128][100 bf16] (25.6 KB, aliases staging) ----
  __bf16* epi = (__bf16*)smem;
  #pragma unroll
  for (int ni = 0; ni < 3; ni++) {
    #pragma unroll
    for (int mi = 0; mi < 4; mi++) {
      const int m  = wr * 64 + mi * 16 + l16;
      const int nbse = wc * 48 + ni * 16 + kg * 4;
      bf16x4 v4;
      #pragma unroll
      for (int r = 0; r < 4; r++)
        v4[r] = (__bf16)__float2bfloat16(acc[ni][mi][r] + biasLds[nbse + r]);
      *(bf16x4*)(epi + m * 100 + nbse) = v4;
    }
  }
  __syncthreads();

  // softmax each (pixel, p-row) and scatter to its consumer
  const float scale = 0.17677669529663687f; // 32^-0.5
  #pragma unroll
  for (int it = 0; it < 5; it++) {
    const int u = it * 256 + tid;
    if (u < 1152) {
      const int m = u & 127, p = u >> 7;
      const uint32_t* rp = (const uint32_t*)(epi + m * 100 + p * 10);
      float v[9];
      #pragma unroll
      for (int t2 = 0; t2 < 4; t2++) {
        uint32_t bits = rp[t2];
        v[2 * t2]     = __uint_as_float(bits << 16) * scale;
        v[2 * t2 + 1] = __uint_as_float(bits & 0xffff0000u) * scale;
      }
      v[8] = __uint_as_float(rp[4] << 16) * scale;
      float mx = -1e30f;
      #pragma unroll
      for (int q = 0; q < 9; q++) mx = fmaxf(mx, v[q]);
      float s = 0.f;
      #pragma unroll
      for (int q = 0; q < 9; q++) { v[q] = __expf(v[q] - mx); s += v[q]; }
      const float inv = 1.f / s;
      #pragma unroll
      for (int q = 0; q < 9; q++) v[q] *= inv;

      const int mg = m0 + m;
      const int b = mg / HW, yx = mg % HW;
      const int y = yx / WID, x = yx % WID;
      const int i = p / 3, j = p % 3;
      const int yC = y + i - 1, xC = x + j - 1;
      if ((unsigned)yC < HGT && (unsigned)xC < WID) {
        uint32_t* dst = (uint32_t*)(attn2 +
            (size_t)(b * HW + yC * WID + xC) * NATT_W + h * 96 + p * 10);
        union { __bf16 hh[2]; uint32_t u32; } pk;
        #pragma unroll
        for (int k = 0; k < 4; k++) {
          pk.hh[0] = (__bf16)__float2bfloat16(v[2 * k]);
          pk.hh[1] = (__bf16)__float2bfloat16(v[2 * k + 1]);
          dst[k] = pk.u32;
        }
        pk.hh[0] = (__bf16)__float2bfloat16(v[8]);
        pk.hh[1] = (__bf16)0.f;
        dst[4] = pk.u32;
      }
    }
  }
}

// ---------------------------------------------------------------------------
// fold_fused: collapse (pure adds, probs pre-softmaxed consumer-major) + apply.
// Phase 1: thread = (pixel, head), tid<192: 12 contiguous dwordx4 from
//   attn2[pix][head*96..], accumulate 5x5 W (mask OOB-center rows at borders).
// Phase 2: identical to round-9 validated form.
// gather quirk: tap(a,e) = vproj[b, row=x+e-2, col=y+a-2].
// ---------------------------------------------------------------------------
__global__ __launch_bounds__(256) void fold_fused(
    const hbf16* __restrict__ attn2,   // [NPIX, NATT_W] bf16 PROBS (consumer-major)
    const hbf16* __restrict__ vprojb,  // [NPIX, 384] bf16
    hbf16* __restrict__ foldedb)       // [NPIX, 384] bf16
{
  __shared__ float Wl[16 * HEADS * 25];   // 19200 B

  const int b    = blockIdx.x & 7;
  const int tile = blockIdx.x >> 3;        // 0..195
  const int tx = tile % 14, ty = tile / 14;
  const int x0 = tx * 4, y0 = ty * 4;
  const int bofs = b * HW;
  const int tid = threadIdx.x;
  const bool interior = (tx >= 1) && (tx <= 12) && (ty >= 1) && (ty <= 12);

  // ---- phase 1: accumulate effective kernels (pure adds) ----
  if (tid < 192) {
    const int pixL = tid / HEADS, head = tid - pixL * HEADS;
    const int y = y0 + (pixL >> 2), x = x0 + (pixL & 3);

    const u32x4* base = (const u32x4*)(attn2 +
        (size_t)(bofs + y * WID + x) * NATT_W + head * 96);
    u32x4 dv[12];
    #pragma unroll
    for (int k = 0; k < 12; k++) dv[k] = base[k];

    float W[25];
    #pragma unroll
    for (int k = 0; k < 25; k++) W[k] = 0.f;

    #pragma unroll
    for (int r = 0; r < 9; r++) {
      const int i = r / 3, j = r % 3;
      if (!interior) {
        const int hh = y - i + 1, ww = x - j + 1;
        if (!((unsigned)hh < HGT && (unsigned)ww < WID)) continue;
      }
      float v[9];
      #pragma unroll
      for (int t = 0; t < 4; t++) {
        const int k = 5 * r + t;
        const uint32_t bits = dv[k >> 2][k & 3];
        v[2 * t]     = __uint_as_float(bits << 16);
        v[2 * t + 1] = __uint_as_float(bits & 0xffff0000u);
      }
      {
        const int k = 5 * r + 4;
        v[8] = __uint_as_float(dv[k >> 2][k & 3] << 16);
      }
      #pragma unroll
      for (int ip = 0; ip < 3; ip++)
        #pragma unroll
        for (int jp = 0; jp < 3; jp++)
          W[(ip - i + 2) * 5 + (jp - j + 2)] += v[ip * 3 + jp];
    }
    float* o = &Wl[tid * 25];
    #pragma unroll
    for (int k = 0; k < 25; k++) o[k] = W[k];
  }
  __syncthreads();

  // ---- phase 2: apply 5x5 kernels (round-9 validated) ----
  const int pixL = tid >> 4;          // 0..15
  const int ch16 = tid & 15;
  const int y = y0 + (pixL >> 2), x = x0 + (pixL & 3);
  const size_t pixofs = (size_t)(bofs + y * WID + x);
  const hbf16* vb0 = vprojb + (size_t)(bofs + (x - 2) * WID + (y - 2)) * NVAL;

  #pragma unroll
  for (int it = 0; it < 3; it++) {
    const int c0 = ch16 * 8 + it * 128;
    const int head = c0 >> 5;
    const float* Wp = &Wl[(pixL * HEADS + head) * 25];
    float acc[8];
    #pragma unroll
    for (int k = 0; k < 8; k++) acc[k] = 0.f;

    if (interior) {
      #pragma unroll
      for (int a = 0; a < 5; a++)
        #pragma unroll
        for (int e = 0; e < 5; e++) {
          const float w_ = Wp[a * 5 + e];
          const uint32_t* v = (const uint32_t*)(vb0 + (e * WID + a) * NVAL + c0);
          uint32_t b0 = v[0], b1 = v[1], b2 = v[2], b3 = v[3];
          acc[0] += w_ * __uint_as_float(b0 << 16);
          acc[1] += w_ * __uint_as_float(b0 & 0xffff0000u);
          acc[2] += w_ * __uint_as_float(b1 << 16);
          acc[3] += w_ * __uint_as_float(b1 & 0xffff0000u);
          acc[4] += w_ * __uint_as_float(b2 << 16);
          acc[5] += w_ * __uint_as_float(b2 & 0xffff0000u);
          acc[6] += w_ * __uint_as_float(b3 << 16);
          acc[7] += w_ * __uint_as_float(b3 & 0xffff0000u);
        }
    } else {
      #pragma unroll
      for (int a = 0; a < 5; a++) {
        const int wi = y + a - 2;
        #pragma unroll
        for (int e = 0; e < 5; e++) {
          const int hi = x + e - 2;
          if (wi >= 0 && wi < WID && hi >= 0 && hi < HGT) {
            const float w_ = Wp[a * 5 + e];
            const uint32_t* v = (const uint32_t*)(
                vprojb + (size_t)(bofs + hi * WID + wi) * NVAL + c0);
            uint32_t b0 = v[0], b1 = v[1], b2 = v[2], b3 = v[3];
            acc[0] += w_ * __uint_as_float(b0 << 16);
            acc[1] += w_ * __uint_as_float(b0 & 0xffff0000u);
            acc[2] += w_ * __uint_as_float(b1 << 16);
            acc[3] += w_ * __uint_as_float(b1 & 0xffff0000u);
            acc[4] += w_ * __uint_as_float(b2 << 16);
            acc[5] += w_ * __uint_as_float(b2 & 0xffff0000u);
            acc[6] += w_ * __uint_as_float(b3 << 16);
            acc[7] += w_ * __uint_as_float(b3 & 0xffff0000u);
          }
        }
      }
    }

    bf16x8 o;
    #pragma unroll
    for (int k = 0; k < 8; k++) o[k] = (__bf16)__float2bfloat16(acc[k]);
    *(bf16x8*)(foldedb + pixofs * NVAL + c0) = o;
  }
}

// ---------------------------------------------------------------------------
extern "C" void kernel_launch(void* const* d_in, const int* in_sizes, int n_in,
                              void* d_out, int out_size, void* d_ws, size_t ws_size,
                              hipStream_t stream)
{
  const float* x  = (const float*)d_in[0];
  const float* Wv = (const float*)d_in[1];
  const float* Wa = (const float*)d_in[2];
  const float* ba = (const float*)d_in[3];
  const float* Wp = (const float*)d_in[4];
  const float* bp = (const float*)d_in[5];
  float* out = (float*)d_out;

  char* w = (char*)d_ws;
  const size_t ATTN_B  = (size_t)NPIX * NATT_W * 2;     // 57.8 MB
  const size_t VPROJ_B = (size_t)NPIX * NVAL * 2;       // 19.3 MB
  const size_t XB_B    = (size_t)NPIX * CIN * 2;        // 19.3 MB
  hbf16* attn2  = (hbf16*)w;
  hbf16* vprojb = (hbf16*)(w + ATTN_B);
  hbf16* xb     = (hbf16*)(w + ATTN_B + VPROJ_B);
  hbf16* wcat   = (hbf16*)(w + ATTN_B + VPROJ_B + XB_B);
  hbf16* wpb    = wcat + (size_t)NQKV * CIN;
  float* bcat   = (float*)(wpb + (size_t)CIN * CIN);
  hbf16* foldedb = xb;            // reuse: xb dead after the projections

  // 1) all preprocessing
  prep_all<<<dim3(NB_CONVX + NB_WQKV + NB_WP), 256, 0, stream>>>(
      x, Wv, Wa, ba, Wp, xb, wcat, bcat, wpb);
  // 2) value projection (chunked-XCD grid 8*25*3)
  gemm_fused<0><<<dim3(600), 256, 0, stream>>>(xb, wcat, bcat, vprojb, nullptr);
  // 3) attn logits + fused softmax, consumer-major scatter (8*25*12)
  gemm_attn<<<dim3(2400), 256, 0, stream>>>(xb, wcat, bcat, attn2);
  // 4) collapse + apply + fold -> foldedb bf16
  fold_fused<<<dim3(8 * 196), 256, 0, stream>>>(attn2, vprojb, foldedb);
  // 5) output projection, transpose-out to [B, 384, HW]
  gemm_fused<1><<<dim3(600), 256, 0, stream>>>(foldedb, wpb, bp, nullptr, out);
}

// Round 14
// 121.342 us; speedup vs baseline: 1.1813x; 1.1813x over previous
//
#include <hip/hip_runtime.h>
#include <hip/hip_bf16.h>
#include <math.h>

#define BATCH 8
#define CIN   384
#define HEADS 12
#define HGT   56
#define WID   56
#define HW    3136                 // 56*56
#define NPIX  (BATCH*HW)           // 25088
#define NVAL  384
#define NATT_W 1152                // padded attn width: head*96 + p*10 + q
#define NQKV  1536                 // 384 + 1152 = 12*128
#define KSTEPS (CIN/32)            // 12
#define MB_TOT 196                 // m-tiles (NPIX/128)

typedef __bf16 bf16x8 __attribute__((ext_vector_type(8)));
typedef __bf16 bf16x4 __attribute__((ext_vector_type(4)));
typedef float f32x4 __attribute__((ext_vector_type(4)));
typedef uint32_t u32x4 __attribute__((ext_vector_type(4)));
typedef uint32_t u32x2 __attribute__((ext_vector_type(2)));
typedef __hip_bfloat16 hbf16;

__device__ __forceinline__ void gload_lds16(const void* g, void* l) {
  __builtin_amdgcn_global_load_lds(
      (const __attribute__((address_space(1))) void*)g,
      (__attribute__((address_space(3))) void*)l, 16, 0, 0);
}

// ---------------------------------------------------------------------------
// prep_all: one kernel for all preprocessing.
// ---------------------------------------------------------------------------
#define NB_CONVX 9408
#define NB_WQKV  2304
#define NB_WP    576
__global__ __launch_bounds__(256) void prep_all(
    const float* __restrict__ x,
    const float* __restrict__ Wv, const float* __restrict__ Wa,
    const float* __restrict__ ba, const float* __restrict__ Wp,
    hbf16* __restrict__ xb, hbf16* __restrict__ wcat,
    float* __restrict__ bcat, hbf16* __restrict__ wpb)
{
  const int bid = blockIdx.x;
  const int tid = threadIdx.x;
  if (bid < NB_CONVX) {
    __shared__ float s[32][33];
    const int xt = bid % 98;
    const int yt = (bid / 98) % 12;
    const int b  = bid / (98 * 12);
    const int hw0 = xt * 32, c0 = yt * 32;
    const int tx = tid & 31, ty = tid >> 5;
    #pragma unroll
    for (int i = 0; i < 4; i++) {
      int c = c0 + ty + i * 8;
      s[ty + i * 8][tx] = x[((size_t)b * CIN + c) * HW + hw0 + tx];
    }
    __syncthreads();
    #pragma unroll
    for (int i = 0; i < 4; i++) {
      int hw = hw0 + ty + i * 8;
      xb[((size_t)b * HW + hw) * CIN + c0 + tx] =
          __float2bfloat16(s[tx][ty + i * 8]);
    }
  } else if (bid < NB_CONVX + NB_WQKV) {
    const int i = (bid - NB_CONVX) * 256 + tid;
    if (i < NQKV * CIN) {
      int n = i / CIN, k = i % CIN;
      float v = 0.f;
      if (n < NVAL) {
        v = Wv[(size_t)n * CIN + k];
      } else {
        int a = n - NVAL;                 // 0..1151
        int head = a / 96, r = a % 96, p = r / 10, q = r % 10;
        if (p < 9 && q < 9)
          v = Wa[(size_t)(head * 81 + p * 9 + q) * CIN + k];
      }
      wcat[i] = __float2bfloat16(v);
    }
    if (i < NQKV) {
      float bv = 0.f;
      if (i >= NVAL) {
        int a = i - NVAL;
        int head = a / 96, r = a % 96, p = r / 10, q = r % 10;
        if (p < 9 && q < 9) bv = ba[head * 81 + p * 9 + q];
      }
      bcat[i] = bv;
    }
  } else {
    const int i = (bid - NB_CONVX - NB_WQKV) * 256 + tid;
    if (i < CIN * CIN) wpb[i] = __float2bfloat16(Wp[i]);
  }
}

// ---------------------------------------------------------------------------
// Double-buffered MFMA GEMM, 128x128 tile, BK=32, 4 waves, 4 blocks/CU.
// 1-D XCD-grouped grid (round-12 validated): m%8 fixed by wgid%8, n-fastest.
// MODE 0 (QKV): swapped acc; bf16 epilogue via swizzled LDS -> vproj/attn.
// MODE 1 (P): natural acc; f32 epilogue LDS-transposed -> out[b, n, hw].
// ---------------------------------------------------------------------------
template<int MODE>
__global__ __launch_bounds__(256, 4) void gemm_fused(
    const hbf16* __restrict__ A_,
    const hbf16* __restrict__ Bt_,
    const float* __restrict__ bias,
    hbf16* __restrict__ ovp,
    hbf16* __restrict__ oat,
    float* __restrict__ oput)
{
  __shared__ __align__(16) char smem[33280];
  const __bf16* A  = (const __bf16*)A_;
  const __bf16* Bt = (const __bf16*)Bt_;

  const int tid  = threadIdx.x;
  const int wave = tid >> 6, lane = tid & 63;
  const int wr = wave >> 1, wc = wave & 1;
  const int l16 = lane & 15, kg = lane >> 4;

  // XCD-grouped (mb, nb) from 1-D wgid
  const int NBN   = (MODE == 0) ? (NQKV / 128) : (NVAL / 128);  // 12 or 3
  const int FULLB = 8 * NBN * (MB_TOT / 8);                      // full groups
  int mb, nb;
  {
    const int wgid = blockIdx.x;
    if (wgid < FULLB) {
      const int xc = wgid & 7, r = wgid >> 3;
      nb = r % NBN;
      mb = (r / NBN) * 8 + xc;
    } else {
      const int l = wgid - FULLB;
      nb = l >> 2;
      mb = (MB_TOT & ~7) + (l & 3);
    }
  }
  const int m0 = mb * 128, n0 = nb * 128;

  float* biasLds = (float*)(smem + 32768);
  if (tid < 128) biasLds[tid] = bias[n0 + tid];

  const int srow = tid >> 2;
  const int skb  = (tid & 3) * 16;

  f32x4 acc[4][4] = {};

  auto stage = [&](int k0, int buf) {
    const char* gA = (const char*)(A  + (size_t)m0 * CIN + k0);
    const char* gB = (const char*)(Bt + (size_t)n0 * CIN + k0);
    char* lA = smem + buf * 16384;
    char* lB = smem + buf * 16384 + 8192;
    #pragma unroll
    for (int p = 0; p < 2; p++) {
      int row = p * 64 + srow;
      gload_lds16(gA + (size_t)row * (CIN * 2) + skb, lA + p * 4096 + wave * 1024);
      gload_lds16(gB + (size_t)row * (CIN * 2) + skb, lB + p * 4096 + wave * 1024);
    }
  };

  stage(0, 0);
  __syncthreads();

  for (int t = 0; t < KSTEPS; ++t) {
    const int buf = t & 1;
    if (t + 1 < KSTEPS) stage((t + 1) * 32, buf ^ 1);

    const __bf16* As = (const __bf16*)(smem + buf * 16384);
    const __bf16* Bs = (const __bf16*)(smem + buf * 16384 + 8192);
    bf16x8 af[4], bfr[4];
    #pragma unroll
    for (int mi = 0; mi < 4; mi++)
      af[mi] = *(const bf16x8*)(As + (wr * 64 + mi * 16 + l16) * 32 + kg * 8);
    #pragma unroll
    for (int ni = 0; ni < 4; ni++)
      bfr[ni] = *(const bf16x8*)(Bs + (wc * 64 + ni * 16 + l16) * 32 + kg * 8);
    #pragma unroll
    for (int mi = 0; mi < 4; mi++)
      #pragma unroll
      for (int ni = 0; ni < 4; ni++) {
        if (MODE == 0)
          acc[ni][mi] = __builtin_amdgcn_mfma_f32_16x16x32_bf16(
              bfr[ni], af[mi], acc[ni][mi], 0, 0, 0);
        else
          acc[mi][ni] = __builtin_amdgcn_mfma_f32_16x16x32_bf16(
              af[mi], bfr[ni], acc[mi][ni], 0, 0, 0);
      }
    __syncthreads();
  }

  if (MODE == 0) {
    __bf16* epi = (__bf16*)smem;
    #pragma unroll
    for (int ni = 0; ni < 4; ni++) {
      #pragma unroll
      for (int mi = 0; mi < 4; mi++) {
        const int m  = wr * 64 + mi * 16 + l16;
        const int nb2 = wc * 64 + ni * 16 + kg * 4;
        bf16x4 v4;
        #pragma unroll
        for (int r = 0; r < 4; r++)
          v4[r] = (__bf16)__float2bfloat16(acc[ni][mi][r] + biasLds[nb2 + r]);
        *(bf16x4*)(epi + m * 128 + (nb2 ^ ((m & 7) << 3))) = v4;
      }
    }
    __syncthreads();
    const bool isv = (n0 < NVAL);
    #pragma unroll
    for (int q = 0; q < 8; q++) {
      const int cid = q * 256 + tid;
      const int m = cid >> 4, nc = cid & 15;
      const int nloc = nc * 8;
      bf16x8 v = *(const bf16x8*)(epi + m * 128 + (nloc ^ ((m & 7) << 3)));
      const int mg = m0 + m;
      if (isv)
        *(bf16x8*)(ovp + (size_t)mg * NVAL + n0 + nloc) = v;
      else
        *(bf16x8*)(oat + (size_t)mg * NATT_W + (n0 - NVAL) + nloc) = v;
    }
  } else {
    float* epi = (float*)smem;
    #pragma unroll
    for (int p = 0; p < 2; p++) {
      if (p) __syncthreads();
      if (wr == p) {
        #pragma unroll
        for (int mi = 0; mi < 4; mi++) {
          #pragma unroll
          for (int ni = 0; ni < 4; ni++) {
            const int n  = wc * 64 + ni * 16 + l16;
            const int ml = mi * 16 + kg * 4;
            f32x4 v;
            #pragma unroll
            for (int r = 0; r < 4; r++) v[r] = acc[mi][ni][r] + biasLds[n];
            *(f32x4*)(epi + n * 64 + (ml ^ ((n & 7) << 2))) = v;
          }
        }
      }
      __syncthreads();
      #pragma unroll
      for (int q = 0; q < 8; q++) {
        const int cid = q * 256 + tid;
        const int n = cid >> 4, mc = cid & 15;
        const int ml = mc * 4;
        f32x4 v = *(const f32x4*)(epi + n * 64 + (ml ^ ((n & 7) << 2)));
        const int mg = m0 + p * 64 + ml;
        const int b = mg / HW, hw = mg % HW;
        *(f32x4*)(oput + ((size_t)b * NVAL + n0 + n) * HW + hw) = v;
      }
    }
  }
}

// ---------------------------------------------------------------------------
// fold_fused (round-9 structure, loads explicitly vectorized):
// 4x4-pixel tiles, 256 threads, 19.2 KB LDS. blockIdx&7 = batch (XCD).
// Phase 1: thread = (pixel, head), tid<192: softmax 9 rows of 10 bf16.
//   Rows are 20 B at byte offset pix*2304 + head*192 + r*20: 8B-aligned for
//   even r at +0, for odd r at +4 -> alignment-aware dwordx2 loads (3 issues
//   per row instead of 5).
// Phase 2: 25-tap vproj gather; every tap address is 16B-aligned
//   (row base pixel*768B, c0*2 multiple of 16) -> single u32x4 per tap
//   (75 load issues instead of 300).
// gather quirk: tap(a,e) = vproj[b, row=x+e-2, col=y+a-2].
// ---------------------------------------------------------------------------
__global__ __launch_bounds__(256) void fold_fused(
    const hbf16* __restrict__ attnb,   // [NPIX, NATT_W] bf16 logits
    const hbf16* __restrict__ vprojb,  // [NPIX, 384] bf16
    hbf16* __restrict__ foldedb)       // [NPIX, 384] bf16
{
  __shared__ float Wl[16 * HEADS * 25];   // 19200 B

  const int b    = blockIdx.x & 7;
  const int tile = blockIdx.x >> 3;        // 0..195
  const int tx = tile % 14, ty = tile / 14;
  const int x0 = tx * 4, y0 = ty * 4;
  const int bofs = b * HW;
  const int tid = threadIdx.x;
  const bool interior = (tx >= 1) && (tx <= 12) && (ty >= 1) && (ty <= 12);
  const float scale = 0.17677669529663687f; // 32^-0.5

  // ---- phase 1: build effective kernels ----
  if (tid < 192) {
    const int pixL = tid / HEADS, head = tid - pixL * HEADS;
    const int y = y0 + (pixL >> 2), x = x0 + (pixL & 3);

    float W[25];
    #pragma unroll
    for (int k = 0; k < 25; k++) W[k] = 0.f;

    auto docenter = [&](int i, int j) {
      const int r = i * 3 + j;
      const uint32_t* rp = (const uint32_t*)(attnb +
          (size_t)(bofs + (y - i + 1) * WID + (x - j + 1)) * NATT_W +
          head * 96 + r * 10);
      uint32_t d[5];
      if ((r & 1) == 0) {          // base 8B-aligned
        u32x2 a0 = *(const u32x2*)(rp);
        u32x2 a1 = *(const u32x2*)(rp + 2);
        d[0] = a0[0]; d[1] = a0[1]; d[2] = a1[0]; d[3] = a1[1];
        d[4] = rp[4];
      } else {                      // base+4 is 8B-aligned
        d[0] = rp[0];
        u32x2 a0 = *(const u32x2*)(rp + 1);
        u32x2 a1 = *(const u32x2*)(rp + 3);
        d[1] = a0[0]; d[2] = a0[1]; d[3] = a1[0]; d[4] = a1[1];
      }
      float v[9];
      #pragma unroll
      for (int u = 0; u < 4; u++) {
        v[2 * u]     = __uint_as_float(d[u] << 16) * scale;
        v[2 * u + 1] = __uint_as_float(d[u] & 0xffff0000u) * scale;
      }
      v[8] = __uint_as_float(d[4] << 16) * scale;
      float m = -1e30f;
      #pragma unroll
      for (int q = 0; q < 9; q++) m = fmaxf(m, v[q]);
      float s = 0.f;
      #pragma unroll
      for (int q = 0; q < 9; q++) { v[q] = __expf(v[q] - m); s += v[q]; }
      const float inv = 1.f / s;
      #pragma unroll
      for (int ip = 0; ip < 3; ip++)
        #pragma unroll
        for (int jp = 0; jp < 3; jp++)
          W[(ip - i + 2) * 5 + (jp - j + 2)] += v[ip * 3 + jp] * inv;
    };

    if (interior) {
      #pragma unroll
      for (int i = 0; i < 3; i++)
        #pragma unroll
        for (int j = 0; j < 3; j++)
          docenter(i, j);
    } else {
      #pragma unroll
      for (int i = 0; i < 3; i++)
        #pragma unroll
        for (int j = 0; j < 3; j++) {
          const int hh = y - i + 1, ww = x - j + 1;
          if (hh >= 0 && hh < HGT && ww >= 0 && ww < WID) docenter(i, j);
        }
    }
    float* o = &Wl[tid * 25];
    #pragma unroll
    for (int k = 0; k < 25; k++) o[k] = W[k];
  }
  __syncthreads();

  // ---- phase 2: apply 5x5 kernels ----
  const int pixL = tid >> 4;          // 0..15
  const int ch16 = tid & 15;
  const int y = y0 + (pixL >> 2), x = x0 + (pixL & 3);
  const size_t pixofs = (size_t)(bofs + y * WID + x);
  // top-left tap base honoring the transpose quirk: pixel (row=x-2, col=y-2);
  // tap (a,e) adds e*WID + a.
  const hbf16* vb0 = vprojb + (size_t)(bofs + (x - 2) * WID + (y - 2)) * NVAL;

  #pragma unroll
  for (int it = 0; it < 3; it++) {
    const int c0 = ch16 * 8 + it * 128;
    const int head = c0 >> 5;
    const float* Wp = &Wl[(pixL * HEADS + head) * 25];
    float acc[8];
    #pragma unroll
    for (int k = 0; k < 8; k++) acc[k] = 0.f;

    if (interior) {
      #pragma unroll
      for (int a = 0; a < 5; a++)
        #pragma unroll
        for (int e = 0; e < 5; e++) {
          const float w_ = Wp[a * 5 + e];
          const u32x4 vv = *(const u32x4*)(vb0 + (e * WID + a) * NVAL + c0);
          acc[0] += w_ * __uint_as_float(vv[0] << 16);
          acc[1] += w_ * __uint_as_float(vv[0] & 0xffff0000u);
          acc[2] += w_ * __uint_as_float(vv[1] << 16);
          acc[3] += w_ * __uint_as_float(vv[1] & 0xffff0000u);
          acc[4] += w_ * __uint_as_float(vv[2] << 16);
          acc[5] += w_ * __uint_as_float(vv[2] & 0xffff0000u);
          acc[6] += w_ * __uint_as_float(vv[3] << 16);
          acc[7] += w_ * __uint_as_float(vv[3] & 0xffff0000u);
        }
    } else {
      #pragma unroll
      for (int a = 0; a < 5; a++) {
        const int wi = y + a - 2;
        #pragma unroll
        for (int e = 0; e < 5; e++) {
          const int hi = x + e - 2;
          if (wi >= 0 && wi < WID && hi >= 0 && hi < HGT) {
            const float w_ = Wp[a * 5 + e];
            const u32x4 vv = *(const u32x4*)(
                vprojb + (size_t)(bofs + hi * WID + wi) * NVAL + c0);
            acc[0] += w_ * __uint_as_float(vv[0] << 16);
            acc[1] += w_ * __uint_as_float(vv[0] & 0xffff0000u);
            acc[2] += w_ * __uint_as_float(vv[1] << 16);
            acc[3] += w_ * __uint_as_float(vv[1] & 0xffff0000u);
            acc[4] += w_ * __uint_as_float(vv[2] << 16);
            acc[5] += w_ * __uint_as_float(vv[2] & 0xffff0000u);
            acc[6] += w_ * __uint_as_float(vv[3] << 16);
            acc[7] += w_ * __uint_as_float(vv[3] & 0xffff0000u);
          }
        }
      }
    }

    bf16x8 o;
    #pragma unroll
    for (int k = 0; k < 8; k++) o[k] = (__bf16)__float2bfloat16(acc[k]);
    *(bf16x8*)(foldedb + pixofs * NVAL + c0) = o;
  }
}

// ---------------------------------------------------------------------------
extern "C" void kernel_launch(void* const* d_in, const int* in_sizes, int n_in,
                              void* d_out, int out_size, void* d_ws, size_t ws_size,
                              hipStream_t stream)
{
  const float* x  = (const float*)d_in[0];
  const float* Wv = (const float*)d_in[1];
  const float* Wa = (const float*)d_in[2];
  const float* ba = (const float*)d_in[3];
  const float* Wp = (const float*)d_in[4];
  const float* bp = (const float*)d_in[5];
  float* out = (float*)d_out;

  char* w = (char*)d_ws;
  const size_t ATTN_B  = (size_t)NPIX * NATT_W * 2;     // 57.8 MB
  const size_t VPROJ_B = (size_t)NPIX * NVAL * 2;       // 19.3 MB
  const size_t XB_B    = (size_t)NPIX * CIN * 2;        // 19.3 MB
  hbf16* attnb  = (hbf16*)w;
  hbf16* vprojb = (hbf16*)(w + ATTN_B);
  hbf16* xb     = (hbf16*)(w + ATTN_B + VPROJ_B);
  hbf16* wcat   = (hbf16*)(w + ATTN_B + VPROJ_B + XB_B);
  hbf16* wpb    = wcat + (size_t)NQKV * CIN;
  float* bcat   = (float*)(wpb + (size_t)CIN * CIN);
  hbf16* foldedb = xb;            // reuse: xb dead after the QKV GEMM

  // 1) all preprocessing in one kernel
  prep_all<<<dim3(NB_CONVX + NB_WQKV + NB_WP), 256, 0, stream>>>(
      x, Wv, Wa, ba, Wp, xb, wcat, bcat, wpb);
  // 2) fused V+A projection (XCD-grouped 1-D grid: 196 m-tiles x 12 n-tiles)
  gemm_fused<0><<<dim3(MB_TOT * (NQKV / 128)), 256, 0, stream>>>(
      xb, wcat, bcat, vprojb, attnb, nullptr);
  // 3) softmax + collapse + apply + fold -> foldedb bf16
  fold_fused<<<dim3(8 * 196), 256, 0, stream>>>(attnb, vprojb, foldedb);
  // 4) output projection (XCD-grouped: 196 x 3), transpose-out to [B,384,HW]
  gemm_fused<1><<<dim3(MB_TOT * (NVAL / 128)), 256, 0, stream>>>(
      foldedb, wpb, bp, nullptr, nullptr, out);
}

// Round 15
// 114.675 us; speedup vs baseline: 1.2500x; 1.0581x over previous
//
#include <hip/hip_runtime.h>
#include <hip/hip_bf16.h>
#include <math.h>

#define BATCH 8
#define CIN   384
#define HEADS 12
#define HGT   56
#define WID   56
#define HW    3136                 // 56*56
#define NPIX  (BATCH*HW)           // 25088
#define NVAL  384
#define NATT_W 1152                // padded attn width: head*96 + p*10 + q
#define NQKV  1536                 // 384 + 1152 = 12*128
#define KSTEPS (CIN/32)            // 12
#define MB_TOT 196                 // m-tiles (NPIX/128)

typedef __bf16 bf16x8 __attribute__((ext_vector_type(8)));
typedef __bf16 bf16x4 __attribute__((ext_vector_type(4)));
typedef float f32x4 __attribute__((ext_vector_type(4)));
typedef uint32_t u32x4 __attribute__((ext_vector_type(4)));
typedef uint32_t u32x2 __attribute__((ext_vector_type(2)));
typedef __hip_bfloat16 hbf16;

__device__ __forceinline__ void gload_lds16(const void* g, void* l) {
  __builtin_amdgcn_global_load_lds(
      (const __attribute__((address_space(1))) void*)g,
      (__attribute__((address_space(3))) void*)l, 16, 0, 0);
}

// ---------------------------------------------------------------------------
// prep_all: one kernel for all preprocessing.
// ---------------------------------------------------------------------------
#define NB_CONVX 9408
#define NB_WQKV  2304
#define NB_WP    576
__global__ __launch_bounds__(256) void prep_all(
    const float* __restrict__ x,
    const float* __restrict__ Wv, const float* __restrict__ Wa,
    const float* __restrict__ ba, const float* __restrict__ Wp,
    hbf16* __restrict__ xb, hbf16* __restrict__ wcat,
    float* __restrict__ bcat, hbf16* __restrict__ wpb)
{
  const int bid = blockIdx.x;
  const int tid = threadIdx.x;
  if (bid < NB_CONVX) {
    __shared__ float s[32][33];
    const int xt = bid % 98;
    const int yt = (bid / 98) % 12;
    const int b  = bid / (98 * 12);
    const int hw0 = xt * 32, c0 = yt * 32;
    const int tx = tid & 31, ty = tid >> 5;
    #pragma unroll
    for (int i = 0; i < 4; i++) {
      int c = c0 + ty + i * 8;
      s[ty + i * 8][tx] = x[((size_t)b * CIN + c) * HW + hw0 + tx];
    }
    __syncthreads();
    #pragma unroll
    for (int i = 0; i < 4; i++) {
      int hw = hw0 + ty + i * 8;
      xb[((size_t)b * HW + hw) * CIN + c0 + tx] =
          __float2bfloat16(s[tx][ty + i * 8]);
    }
  } else if (bid < NB_CONVX + NB_WQKV) {
    const int i = (bid - NB_CONVX) * 256 + tid;
    if (i < NQKV * CIN) {
      int n = i / CIN, k = i % CIN;
      float v = 0.f;
      if (n < NVAL) {
        v = Wv[(size_t)n * CIN + k];
      } else {
        int a = n - NVAL;                 // 0..1151
        int head = a / 96, r = a % 96, p = r / 10, q = r % 10;
        if (p < 9 && q < 9)
          v = Wa[(size_t)(head * 81 + p * 9 + q) * CIN + k];
      }
      wcat[i] = __float2bfloat16(v);
    }
    if (i < NQKV) {
      float bv = 0.f;
      if (i >= NVAL) {
        int a = i - NVAL;
        int head = a / 96, r = a % 96, p = r / 10, q = r % 10;
        if (p < 9 && q < 9) bv = ba[head * 81 + p * 9 + q];
      }
      bcat[i] = bv;
    }
  } else {
    const int i = (bid - NB_CONVX - NB_WQKV) * 256 + tid;
    if (i < CIN * CIN) wpb[i] = __float2bfloat16(Wp[i]);
  }
}

// ---------------------------------------------------------------------------
// Double-buffered MFMA GEMM, 128x128 tile, BK=32, 4 waves, 4 blocks/CU.
// 1-D XCD-grouped grid (round-12 validated): m%8 fixed by wgid%8, n-fastest.
// MODE 0 (QKV): swapped acc; bf16 epilogue via swizzled LDS -> vproj/attn.
// MODE 1 (P): natural acc; f32 epilogue LDS-transposed -> out[b, n, hw].
// ---------------------------------------------------------------------------
template<int MODE>
__global__ __launch_bounds__(256, 4) void gemm_fused(
    const hbf16* __restrict__ A_,
    const hbf16* __restrict__ Bt_,
    const float* __restrict__ bias,
    hbf16* __restrict__ ovp,
    hbf16* __restrict__ oat,
    float* __restrict__ oput)
{
  __shared__ __align__(16) char smem[33280];
  const __bf16* A  = (const __bf16*)A_;
  const __bf16* Bt = (const __bf16*)Bt_;

  const int tid  = threadIdx.x;
  const int wave = tid >> 6, lane = tid & 63;
  const int wr = wave >> 1, wc = wave & 1;
  const int l16 = lane & 15, kg = lane >> 4;

  // XCD-grouped (mb, nb) from 1-D wgid
  const int NBN   = (MODE == 0) ? (NQKV / 128) : (NVAL / 128);  // 12 or 3
  const int FULLB = 8 * NBN * (MB_TOT / 8);                      // full groups
  int mb, nb;
  {
    const int wgid = blockIdx.x;
    if (wgid < FULLB) {
      const int xc = wgid & 7, r = wgid >> 3;
      nb = r % NBN;
      mb = (r / NBN) * 8 + xc;
    } else {
      const int l = wgid - FULLB;
      nb = l >> 2;
      mb = (MB_TOT & ~7) + (l & 3);
    }
  }
  const int m0 = mb * 128, n0 = nb * 128;

  float* biasLds = (float*)(smem + 32768);
  if (tid < 128) biasLds[tid] = bias[n0 + tid];

  const int srow = tid >> 2;
  const int skb  = (tid & 3) * 16;

  f32x4 acc[4][4] = {};

  auto stage = [&](int k0, int buf) {
    const char* gA = (const char*)(A  + (size_t)m0 * CIN + k0);
    const char* gB = (const char*)(Bt + (size_t)n0 * CIN + k0);
    char* lA = smem + buf * 16384;
    char* lB = smem + buf * 16384 + 8192;
    #pragma unroll
    for (int p = 0; p < 2; p++) {
      int row = p * 64 + srow;
      gload_lds16(gA + (size_t)row * (CIN * 2) + skb, lA + p * 4096 + wave * 1024);
      gload_lds16(gB + (size_t)row * (CIN * 2) + skb, lB + p * 4096 + wave * 1024);
    }
  };

  stage(0, 0);
  __syncthreads();

  for (int t = 0; t < KSTEPS; ++t) {
    const int buf = t & 1;
    if (t + 1 < KSTEPS) stage((t + 1) * 32, buf ^ 1);

    const __bf16* As = (const __bf16*)(smem + buf * 16384);
    const __bf16* Bs = (const __bf16*)(smem + buf * 16384 + 8192);
    bf16x8 af[4], bfr[4];
    #pragma unroll
    for (int mi = 0; mi < 4; mi++)
      af[mi] = *(const bf16x8*)(As + (wr * 64 + mi * 16 + l16) * 32 + kg * 8);
    #pragma unroll
    for (int ni = 0; ni < 4; ni++)
      bfr[ni] = *(const bf16x8*)(Bs + (wc * 64 + ni * 16 + l16) * 32 + kg * 8);
    #pragma unroll
    for (int mi = 0; mi < 4; mi++)
      #pragma unroll
      for (int ni = 0; ni < 4; ni++) {
        if (MODE == 0)
          acc[ni][mi] = __builtin_amdgcn_mfma_f32_16x16x32_bf16(
              bfr[ni], af[mi], acc[ni][mi], 0, 0, 0);
        else
          acc[mi][ni] = __builtin_amdgcn_mfma_f32_16x16x32_bf16(
              af[mi], bfr[ni], acc[mi][ni], 0, 0, 0);
      }
    __syncthreads();
  }

  if (MODE == 0) {
    __bf16* epi = (__bf16*)smem;
    #pragma unroll
    for (int ni = 0; ni < 4; ni++) {
      #pragma unroll
      for (int mi = 0; mi < 4; mi++) {
        const int m  = wr * 64 + mi * 16 + l16;
        const int nb2 = wc * 64 + ni * 16 + kg * 4;
        bf16x4 v4;
        #pragma unroll
        for (int r = 0; r < 4; r++)
          v4[r] = (__bf16)__float2bfloat16(acc[ni][mi][r] + biasLds[nb2 + r]);
        *(bf16x4*)(epi + m * 128 + (nb2 ^ ((m & 7) << 3))) = v4;
      }
    }
    __syncthreads();
    const bool isv = (n0 < NVAL);
    #pragma unroll
    for (int q = 0; q < 8; q++) {
      const int cid = q * 256 + tid;
      const int m = cid >> 4, nc = cid & 15;
      const int nloc = nc * 8;
      bf16x8 v = *(const bf16x8*)(epi + m * 128 + (nloc ^ ((m & 7) << 3)));
      const int mg = m0 + m;
      if (isv)
        *(bf16x8*)(ovp + (size_t)mg * NVAL + n0 + nloc) = v;
      else
        *(bf16x8*)(oat + (size_t)mg * NATT_W + (n0 - NVAL) + nloc) = v;
    }
  } else {
    float* epi = (float*)smem;
    #pragma unroll
    for (int p = 0; p < 2; p++) {
      if (p) __syncthreads();
      if (wr == p) {
        #pragma unroll
        for (int mi = 0; mi < 4; mi++) {
          #pragma unroll
          for (int ni = 0; ni < 4; ni++) {
            const int n  = wc * 64 + ni * 16 + l16;
            const int ml = mi * 16 + kg * 4;
            f32x4 v;
            #pragma unroll
            for (int r = 0; r < 4; r++) v[r] = acc[mi][ni][r] + biasLds[n];
            *(f32x4*)(epi + n * 64 + (ml ^ ((n & 7) << 2))) = v;
          }
        }
      }
      __syncthreads();
      #pragma unroll
      for (int q = 0; q < 8; q++) {
        const int cid = q * 256 + tid;
        const int n = cid >> 4, mc = cid & 15;
        const int ml = mc * 4;
        f32x4 v = *(const f32x4*)(epi + n * 64 + (ml ^ ((n & 7) << 2)));
        const int mg = m0 + p * 64 + ml;
        const int b = mg / HW, hw = mg % HW;
        *(f32x4*)(oput + ((size_t)b * NVAL + n0 + n) * HW + hw) = v;
      }
    }
  }
}

// ---------------------------------------------------------------------------
// fold_fused: softmax + 5x5-collapse + apply + fold, c-SLICED.
// Grid (8*196, 3): blockIdx.x&7 = batch (XCD affinity), blockIdx.x>>3 = 4x4
// pixel tile, blockIdx.y = s = channel slice (c in [s*128, s*128+128),
// heads s*4..s*4+3). 256 threads, 6.4 KB LDS -> no LDS occupancy cap;
// 4704 blocks (18.4/CU) for latency hiding; per-thread phase 2 = 25 taps.
// Phase 1: tid<64 = (pixel, head-local): softmax 9 rows of 10 bf16
//   (alignment-aware dwordx2), accumulate 5x5 W in LDS (per-slice heads).
// Phase 2: thread = (pixel = tid>>4, ch16 = tid&15), c0 = s*128 + ch16*8;
//   taps row-batched: for each e, 5 a-taps loaded (u32x4) before FMA -> 5
//   outstanding loads.
// gather quirk: tap(a,e) = vproj[b, row=x+e-2, col=y+a-2].
// ---------------------------------------------------------------------------
__global__ __launch_bounds__(256) void fold_fused(
    const hbf16* __restrict__ attnb,   // [NPIX, NATT_W] bf16 logits
    const hbf16* __restrict__ vprojb,  // [NPIX, 384] bf16
    hbf16* __restrict__ foldedb)       // [NPIX, 384] bf16
{
  __shared__ float Wl[64 * 25];           // 6400 B: [pix 16][head-local 4][25]

  const int b    = blockIdx.x & 7;
  const int tile = blockIdx.x >> 3;        // 0..195
  const int s    = blockIdx.y;             // c-slice 0..2
  const int tx = tile % 14, ty = tile / 14;
  const int x0 = tx * 4, y0 = ty * 4;
  const int bofs = b * HW;
  const int tid = threadIdx.x;
  const bool interior = (tx >= 1) && (tx <= 12) && (ty >= 1) && (ty <= 12);
  const float scale = 0.17677669529663687f; // 32^-0.5

  // ---- phase 1: build effective kernels (16 pixels x 4 slice-heads) ----
  if (tid < 64) {
    const int pixL = tid >> 2, head = s * 4 + (tid & 3);
    const int y = y0 + (pixL >> 2), x = x0 + (pixL & 3);

    float W[25];
    #pragma unroll
    for (int k = 0; k < 25; k++) W[k] = 0.f;

    auto docenter = [&](int i, int j) {
      const int r = i * 3 + j;
      const uint32_t* rp = (const uint32_t*)(attnb +
          (size_t)(bofs + (y - i + 1) * WID + (x - j + 1)) * NATT_W +
          head * 96 + r * 10);
      uint32_t d[5];
      if ((r & 1) == 0) {          // base 8B-aligned
        u32x2 a0 = *(const u32x2*)(rp);
        u32x2 a1 = *(const u32x2*)(rp + 2);
        d[0] = a0[0]; d[1] = a0[1]; d[2] = a1[0]; d[3] = a1[1];
        d[4] = rp[4];
      } else {                      // base+4 is 8B-aligned
        d[0] = rp[0];
        u32x2 a0 = *(const u32x2*)(rp + 1);
        u32x2 a1 = *(const u32x2*)(rp + 3);
        d[1] = a0[0]; d[2] = a0[1]; d[3] = a1[0]; d[4] = a1[1];
      }
      float v[9];
      #pragma unroll
      for (int u = 0; u < 4; u++) {
        v[2 * u]     = __uint_as_float(d[u] << 16) * scale;
        v[2 * u + 1] = __uint_as_float(d[u] & 0xffff0000u) * scale;
      }
      v[8] = __uint_as_float(d[4] << 16) * scale;
      float m = -1e30f;
      #pragma unroll
      for (int q = 0; q < 9; q++) m = fmaxf(m, v[q]);
      float sum = 0.f;
      #pragma unroll
      for (int q = 0; q < 9; q++) { v[q] = __expf(v[q] - m); sum += v[q]; }
      const float inv = 1.f / sum;
      #pragma unroll
      for (int ip = 0; ip < 3; ip++)
        #pragma unroll
        for (int jp = 0; jp < 3; jp++)
          W[(ip - i + 2) * 5 + (jp - j + 2)] += v[ip * 3 + jp] * inv;
    };

    if (interior) {
      #pragma unroll
      for (int i = 0; i < 3; i++)
        #pragma unroll
        for (int j = 0; j < 3; j++)
          docenter(i, j);
    } else {
      #pragma unroll
      for (int i = 0; i < 3; i++)
        #pragma unroll
        for (int j = 0; j < 3; j++) {
          const int hh = y - i + 1, ww = x - j + 1;
          if (hh >= 0 && hh < HGT && ww >= 0 && ww < WID) docenter(i, j);
        }
    }
    float* o = &Wl[tid * 25];
    #pragma unroll
    for (int k = 0; k < 25; k++) o[k] = W[k];
  }
  __syncthreads();

  // ---- phase 2: apply 5x5 kernels (16 pixels x 16 ch-groups, 1 iter) ----
  const int pixL = tid >> 4;          // 0..15
  const int ch16 = tid & 15;
  const int y = y0 + (pixL >> 2), x = x0 + (pixL & 3);
  const size_t pixofs = (size_t)(bofs + y * WID + x);
  const int c0 = s * 128 + ch16 * 8;
  const float* Wp = &Wl[(pixL * 4 + (ch16 >> 2)) * 25];
  // top-left tap base honoring the transpose quirk: pixel (row=x-2, col=y-2);
  // tap (a,e) adds e*WID + a.
  const hbf16* vb0 = vprojb + (size_t)(bofs + (x - 2) * WID + (y - 2)) * NVAL;

  float acc[8];
  #pragma unroll
  for (int k = 0; k < 8; k++) acc[k] = 0.f;

  if (interior) {
    #pragma unroll
    for (int e = 0; e < 5; e++) {
      u32x4 t[5];
      #pragma unroll
      for (int a = 0; a < 5; a++)
        t[a] = *(const u32x4*)(vb0 + (e * WID + a) * NVAL + c0);
      #pragma unroll
      for (int a = 0; a < 5; a++) {
        const float w_ = Wp[a * 5 + e];
        acc[0] += w_ * __uint_as_float(t[a][0] << 16);
        acc[1] += w_ * __uint_as_float(t[a][0] & 0xffff0000u);
        acc[2] += w_ * __uint_as_float(t[a][1] << 16);
        acc[3] += w_ * __uint_as_float(t[a][1] & 0xffff0000u);
        acc[4] += w_ * __uint_as_float(t[a][2] << 16);
        acc[5] += w_ * __uint_as_float(t[a][2] & 0xffff0000u);
        acc[6] += w_ * __uint_as_float(t[a][3] << 16);
        acc[7] += w_ * __uint_as_float(t[a][3] & 0xffff0000u);
      }
    }
  } else {
    #pragma unroll
    for (int e = 0; e < 5; e++) {
      const int hi = x + e - 2;
      #pragma unroll
      for (int a = 0; a < 5; a++) {
        const int wi = y + a - 2;
        if (wi >= 0 && wi < WID && hi >= 0 && hi < HGT) {
          const float w_ = Wp[a * 5 + e];
          const u32x4 vv = *(const u32x4*)(
              vprojb + (size_t)(bofs + hi * WID + wi) * NVAL + c0);
          acc[0] += w_ * __uint_as_float(vv[0] << 16);
          acc[1] += w_ * __uint_as_float(vv[0] & 0xffff0000u);
          acc[2] += w_ * __uint_as_float(vv[1] << 16);
          acc[3] += w_ * __uint_as_float(vv[1] & 0xffff0000u);
          acc[4] += w_ * __uint_as_float(vv[2] << 16);
          acc[5] += w_ * __uint_as_float(vv[2] & 0xffff0000u);
          acc[6] += w_ * __uint_as_float(vv[3] << 16);
          acc[7] += w_ * __uint_as_float(vv[3] & 0xffff0000u);
        }
      }
    }
  }

  bf16x8 o;
  #pragma unroll
  for (int k = 0; k < 8; k++) o[k] = (__bf16)__float2bfloat16(acc[k]);
  *(bf16x8*)(foldedb + pixofs * NVAL + c0) = o;
}

// ---------------------------------------------------------------------------
extern "C" void kernel_launch(void* const* d_in, const int* in_sizes, int n_in,
                              void* d_out, int out_size, void* d_ws, size_t ws_size,
                              hipStream_t stream)
{
  const float* x  = (const float*)d_in[0];
  const float* Wv = (const float*)d_in[1];
  const float* Wa = (const float*)d_in[2];
  const float* ba = (const float*)d_in[3];
  const float* Wp = (const float*)d_in[4];
  const float* bp = (const float*)d_in[5];
  float* out = (float*)d_out;

  char* w = (char*)d_ws;
  const size_t ATTN_B  = (size_t)NPIX * NATT_W * 2;     // 57.8 MB
  const size_t VPROJ_B = (size_t)NPIX * NVAL * 2;       // 19.3 MB
  const size_t XB_B    = (size_t)NPIX * CIN * 2;        // 19.3 MB
  hbf16* attnb  = (hbf16*)w;
  hbf16* vprojb = (hbf16*)(w + ATTN_B);
  hbf16* xb     = (hbf16*)(w + ATTN_B + VPROJ_B);
  hbf16* wcat   = (hbf16*)(w + ATTN_B + VPROJ_B + XB_B);
  hbf16* wpb    = wcat + (size_t)NQKV * CIN;
  float* bcat   = (float*)(wpb + (size_t)CIN * CIN);
  hbf16* foldedb = xb;            // reuse: xb dead after the QKV GEMM

  // 1) all preprocessing in one kernel
  prep_all<<<dim3(NB_CONVX + NB_WQKV + NB_WP), 256, 0, stream>>>(
      x, Wv, Wa, ba, Wp, xb, wcat, bcat, wpb);
  // 2) fused V+A projection (XCD-grouped 1-D grid: 196 m-tiles x 12 n-tiles)
  gemm_fused<0><<<dim3(MB_TOT * (NQKV / 128)), 256, 0, stream>>>(
      xb, wcat, bcat, vprojb, attnb, nullptr);
  // 3) softmax + collapse + apply + fold (c-sliced) -> foldedb bf16
  fold_fused<<<dim3(8 * 196, 3), 256, 0, stream>>>(attnb, vprojb, foldedb);
  // 4) output projection (XCD-grouped: 196 x 3), transpose-out to [B,384,HW]
  gemm_fused<1><<<dim3(MB_TOT * (NVAL / 128)), 256, 0, stream>>>(
      foldedb, wpb, bp, nullptr, nullptr, out);
}

// Round 16
// 113.670 us; speedup vs baseline: 1.2610x; 1.0088x over previous
//
#include <hip/hip_runtime.h>
#include <hip/hip_bf16.h>
#include <math.h>

#define BATCH 8
#define CIN   384
#define HEADS 12
#define HGT   56
#define WID   56
#define HW    3136                 // 56*56
#define NPIX  (BATCH*HW)           // 25088
#define NVAL  384
#define NATT_W 1152                // padded attn width: head*96 + p*10 + q
#define NQKV  1536                 // 384 + 1152 = 12*128
#define KSTEPS (CIN/32)            // 12
#define MB_TOT 196                 // m-tiles (NPIX/128)

typedef __bf16 bf16x8 __attribute__((ext_vector_type(8)));
typedef __bf16 bf16x4 __attribute__((ext_vector_type(4)));
typedef float f32x4 __attribute__((ext_vector_type(4)));
typedef uint32_t u32x4 __attribute__((ext_vector_type(4)));
typedef uint32_t u32x2 __attribute__((ext_vector_type(2)));
typedef __hip_bfloat16 hbf16;

__device__ __forceinline__ void gload_lds16(const void* g, void* l) {
  __builtin_amdgcn_global_load_lds(
      (const __attribute__((address_space(1))) void*)g,
      (__attribute__((address_space(3))) void*)l, 16, 0, 0);
}

// ---------------------------------------------------------------------------
// prep_all: one kernel for all preprocessing.
// ---------------------------------------------------------------------------
#define NB_CONVX 9408
#define NB_WQKV  2304
#define NB_WP    576
__global__ __launch_bounds__(256) void prep_all(
    const float* __restrict__ x,
    const float* __restrict__ Wv, const float* __restrict__ Wa,
    const float* __restrict__ ba, const float* __restrict__ Wp,
    hbf16* __restrict__ xb, hbf16* __restrict__ wcat,
    float* __restrict__ bcat, hbf16* __restrict__ wpb)
{
  const int bid = blockIdx.x;
  const int tid = threadIdx.x;
  if (bid < NB_CONVX) {
    __shared__ float s[32][33];
    const int xt = bid % 98;
    const int yt = (bid / 98) % 12;
    const int b  = bid / (98 * 12);
    const int hw0 = xt * 32, c0 = yt * 32;
    const int tx = tid & 31, ty = tid >> 5;
    #pragma unroll
    for (int i = 0; i < 4; i++) {
      int c = c0 + ty + i * 8;
      s[ty + i * 8][tx] = x[((size_t)b * CIN + c) * HW + hw0 + tx];
    }
    __syncthreads();
    #pragma unroll
    for (int i = 0; i < 4; i++) {
      int hw = hw0 + ty + i * 8;
      xb[((size_t)b * HW + hw) * CIN + c0 + tx] =
          __float2bfloat16(s[tx][ty + i * 8]);
    }
  } else if (bid < NB_CONVX + NB_WQKV) {
    const int i = (bid - NB_CONVX) * 256 + tid;
    if (i < NQKV * CIN) {
      int n = i / CIN, k = i % CIN;
      float v = 0.f;
      if (n < NVAL) {
        v = Wv[(size_t)n * CIN + k];
      } else {
        int a = n - NVAL;                 // 0..1151
        int head = a / 96, r = a % 96, p = r / 10, q = r % 10;
        if (p < 9 && q < 9)
          v = Wa[(size_t)(head * 81 + p * 9 + q) * CIN + k];
      }
      wcat[i] = __float2bfloat16(v);
    }
    if (i < NQKV) {
      float bv = 0.f;
      if (i >= NVAL) {
        int a = i - NVAL;
        int head = a / 96, r = a % 96, p = r / 10, q = r % 10;
        if (p < 9 && q < 9) bv = ba[head * 81 + p * 9 + q];
      }
      bcat[i] = bv;
    }
  } else {
    const int i = (bid - NB_CONVX - NB_WQKV) * 256 + tid;
    if (i < CIN * CIN) wpb[i] = __float2bfloat16(Wp[i]);
  }
}

// ---------------------------------------------------------------------------
// Double-buffered MFMA GEMM, 128x128 tile, BK=32, 4 waves, 4 blocks/CU.
// 1-D XCD-grouped grid (round-12 validated): m%8 fixed by wgid%8, n-fastest.
// LDS chunk-swizzle (rule #21: linear dest + inverse-swz source + swz read):
//   each 64B row's 4 x 16B chunks are permuted c -> c ^ ((row>>1)&3).
//   Staging: lane loads global chunk (tid&3)^((tid>>3)&3) of its row.
//   Fragment read: chunk kg ^ ((l16>>1)&3). Banks go 8-way -> 2-way (free).
// MODE 0 (QKV): swapped acc; bf16 epilogue via swizzled LDS -> vproj/attn.
// MODE 1 (P): natural acc; f32 epilogue LDS-transposed -> out[b, n, hw].
// ---------------------------------------------------------------------------
template<int MODE>
__global__ __launch_bounds__(256, 4) void gemm_fused(
    const hbf16* __restrict__ A_,
    const hbf16* __restrict__ Bt_,
    const float* __restrict__ bias,
    hbf16* __restrict__ ovp,
    hbf16* __restrict__ oat,
    float* __restrict__ oput)
{
  __shared__ __align__(16) char smem[33280];
  const __bf16* A  = (const __bf16*)A_;
  const __bf16* Bt = (const __bf16*)Bt_;

  const int tid  = threadIdx.x;
  const int wave = tid >> 6, lane = tid & 63;
  const int wr = wave >> 1, wc = wave & 1;
  const int l16 = lane & 15, kg = lane >> 4;

  // XCD-grouped (mb, nb) from 1-D wgid
  const int NBN   = (MODE == 0) ? (NQKV / 128) : (NVAL / 128);  // 12 or 3
  const int FULLB = 8 * NBN * (MB_TOT / 8);                      // full groups
  int mb, nb;
  {
    const int wgid = blockIdx.x;
    if (wgid < FULLB) {
      const int xc = wgid & 7, r = wgid >> 3;
      nb = r % NBN;
      mb = (r / NBN) * 8 + xc;
    } else {
      const int l = wgid - FULLB;
      nb = l >> 2;
      mb = (MB_TOT & ~7) + (l & 3);
    }
  }
  const int m0 = mb * 128, n0 = nb * 128;

  float* biasLds = (float*)(smem + 32768);
  if (tid < 128) biasLds[tid] = bias[n0 + tid];

  const int srow = tid >> 2;
  // source chunk pre-swizzled so LDS-linear dest realizes the swizzled layout
  const int skb  = (((tid & 3) ^ ((tid >> 3) & 3)) * 16);
  // fragment-read chunk swizzle (uniform across mi/ni: (row>>1)&3 == (l16>>1)&3)
  const int csw  = (l16 >> 1) & 3;

  f32x4 acc[4][4] = {};

  auto stage = [&](int k0, int buf) {
    const char* gA = (const char*)(A  + (size_t)m0 * CIN + k0);
    const char* gB = (const char*)(Bt + (size_t)n0 * CIN + k0);
    char* lA = smem + buf * 16384;
    char* lB = smem + buf * 16384 + 8192;
    #pragma unroll
    for (int p = 0; p < 2; p++) {
      int row = p * 64 + srow;
      gload_lds16(gA + (size_t)row * (CIN * 2) + skb, lA + p * 4096 + wave * 1024);
      gload_lds16(gB + (size_t)row * (CIN * 2) + skb, lB + p * 4096 + wave * 1024);
    }
  };

  stage(0, 0);
  __syncthreads();

  for (int t = 0; t < KSTEPS; ++t) {
    const int buf = t & 1;
    if (t + 1 < KSTEPS) stage((t + 1) * 32, buf ^ 1);

    const __bf16* As = (const __bf16*)(smem + buf * 16384);
    const __bf16* Bs = (const __bf16*)(smem + buf * 16384 + 8192);
    bf16x8 af[4], bfr[4];
    #pragma unroll
    for (int mi = 0; mi < 4; mi++)
      af[mi] = *(const bf16x8*)(As + (wr * 64 + mi * 16 + l16) * 32 +
                                (kg ^ csw) * 8);
    #pragma unroll
    for (int ni = 0; ni < 4; ni++)
      bfr[ni] = *(const bf16x8*)(Bs + (wc * 64 + ni * 16 + l16) * 32 +
                                 (kg ^ csw) * 8);
    #pragma unroll
    for (int mi = 0; mi < 4; mi++)
      #pragma unroll
      for (int ni = 0; ni < 4; ni++) {
        if (MODE == 0)
          acc[ni][mi] = __builtin_amdgcn_mfma_f32_16x16x32_bf16(
              bfr[ni], af[mi], acc[ni][mi], 0, 0, 0);
        else
          acc[mi][ni] = __builtin_amdgcn_mfma_f32_16x16x32_bf16(
              af[mi], bfr[ni], acc[mi][ni], 0, 0, 0);
      }
    __syncthreads();
  }

  if (MODE == 0) {
    __bf16* epi = (__bf16*)smem;
    #pragma unroll
    for (int ni = 0; ni < 4; ni++) {
      #pragma unroll
      for (int mi = 0; mi < 4; mi++) {
        const int m  = wr * 64 + mi * 16 + l16;
        const int nb2 = wc * 64 + ni * 16 + kg * 4;
        bf16x4 v4;
        #pragma unroll
        for (int r = 0; r < 4; r++)
          v4[r] = (__bf16)__float2bfloat16(acc[ni][mi][r] + biasLds[nb2 + r]);
        *(bf16x4*)(epi + m * 128 + (nb2 ^ ((m & 7) << 3))) = v4;
      }
    }
    __syncthreads();
    const bool isv = (n0 < NVAL);
    #pragma unroll
    for (int q = 0; q < 8; q++) {
      const int cid = q * 256 + tid;
      const int m = cid >> 4, nc = cid & 15;
      const int nloc = nc * 8;
      bf16x8 v = *(const bf16x8*)(epi + m * 128 + (nloc ^ ((m & 7) << 3)));
      const int mg = m0 + m;
      if (isv)
        *(bf16x8*)(ovp + (size_t)mg * NVAL + n0 + nloc) = v;
      else
        *(bf16x8*)(oat + (size_t)mg * NATT_W + (n0 - NVAL) + nloc) = v;
    }
  } else {
    float* epi = (float*)smem;
    #pragma unroll
    for (int p = 0; p < 2; p++) {
      if (p) __syncthreads();
      if (wr == p) {
        #pragma unroll
        for (int mi = 0; mi < 4; mi++) {
          #pragma unroll
          for (int ni = 0; ni < 4; ni++) {
            const int n  = wc * 64 + ni * 16 + l16;
            const int ml = mi * 16 + kg * 4;
            f32x4 v;
            #pragma unroll
            for (int r = 0; r < 4; r++) v[r] = acc[mi][ni][r] + biasLds[n];
            *(f32x4*)(epi + n * 64 + (ml ^ ((n & 7) << 2))) = v;
          }
        }
      }
      __syncthreads();
      #pragma unroll
      for (int q = 0; q < 8; q++) {
        const int cid = q * 256 + tid;
        const int n = cid >> 4, mc = cid & 15;
        const int ml = mc * 4;
        f32x4 v = *(const f32x4*)(epi + n * 64 + (ml ^ ((n & 7) << 2)));
        const int mg = m0 + p * 64 + ml;
        const int b = mg / HW, hw = mg % HW;
        *(f32x4*)(oput + ((size_t)b * NVAL + n0 + n) * HW + hw) = v;
      }
    }
  }
}

// ---------------------------------------------------------------------------
// fold_fused: softmax + 5x5-collapse + apply + fold, c-SLICED (r15 validated).
// Grid (8*196, 3): blockIdx.x&7 = batch (XCD), blockIdx.x>>3 = 4x4 tile,
// blockIdx.y = s = channel slice. 256 threads, 6.4 KB LDS, 4704 blocks.
// gather quirk: tap(a,e) = vproj[b, row=x+e-2, col=y+a-2].
// ---------------------------------------------------------------------------
__global__ __launch_bounds__(256) void fold_fused(
    const hbf16* __restrict__ attnb,   // [NPIX, NATT_W] bf16 logits
    const hbf16* __restrict__ vprojb,  // [NPIX, 384] bf16
    hbf16* __restrict__ foldedb)       // [NPIX, 384] bf16
{
  __shared__ float Wl[64 * 25];           // 6400 B: [pix 16][head-local 4][25]

  const int b    = blockIdx.x & 7;
  const int tile = blockIdx.x >> 3;        // 0..195
  const int s    = blockIdx.y;             // c-slice 0..2
  const int tx = tile % 14, ty = tile / 14;
  const int x0 = tx * 4, y0 = ty * 4;
  const int bofs = b * HW;
  const int tid = threadIdx.x;
  const bool interior = (tx >= 1) && (tx <= 12) && (ty >= 1) && (ty <= 12);
  const float scale = 0.17677669529663687f; // 32^-0.5

  // ---- phase 1: build effective kernels (16 pixels x 4 slice-heads) ----
  if (tid < 64) {
    const int pixL = tid >> 2, head = s * 4 + (tid & 3);
    const int y = y0 + (pixL >> 2), x = x0 + (pixL & 3);

    float W[25];
    #pragma unroll
    for (int k = 0; k < 25; k++) W[k] = 0.f;

    auto docenter = [&](int i, int j) {
      const int r = i * 3 + j;
      const uint32_t* rp = (const uint32_t*)(attnb +
          (size_t)(bofs + (y - i + 1) * WID + (x - j + 1)) * NATT_W +
          head * 96 + r * 10);
      uint32_t d[5];
      if ((r & 1) == 0) {          // base 8B-aligned
        u32x2 a0 = *(const u32x2*)(rp);
        u32x2 a1 = *(const u32x2*)(rp + 2);
        d[0] = a0[0]; d[1] = a0[1]; d[2] = a1[0]; d[3] = a1[1];
        d[4] = rp[4];
      } else {                      // base+4 is 8B-aligned
        d[0] = rp[0];
        u32x2 a0 = *(const u32x2*)(rp + 1);
        u32x2 a1 = *(const u32x2*)(rp + 3);
        d[1] = a0[0]; d[2] = a0[1]; d[3] = a1[0]; d[4] = a1[1];
      }
      float v[9];
      #pragma unroll
      for (int u = 0; u < 4; u++) {
        v[2 * u]     = __uint_as_float(d[u] << 16) * scale;
        v[2 * u + 1] = __uint_as_float(d[u] & 0xffff0000u) * scale;
      }
      v[8] = __uint_as_float(d[4] << 16) * scale;
      float m = -1e30f;
      #pragma unroll
      for (int q = 0; q < 9; q++) m = fmaxf(m, v[q]);
      float sum = 0.f;
      #pragma unroll
      for (int q = 0; q < 9; q++) { v[q] = __expf(v[q] - m); sum += v[q]; }
      const float inv = 1.f / sum;
      #pragma unroll
      for (int ip = 0; ip < 3; ip++)
        #pragma unroll
        for (int jp = 0; jp < 3; jp++)
          W[(ip - i + 2) * 5 + (jp - j + 2)] += v[ip * 3 + jp] * inv;
    };

    if (interior) {
      #pragma unroll
      for (int i = 0; i < 3; i++)
        #pragma unroll
        for (int j = 0; j < 3; j++)
          docenter(i, j);
    } else {
      #pragma unroll
      for (int i = 0; i < 3; i++)
        #pragma unroll
        for (int j = 0; j < 3; j++) {
          const int hh = y - i + 1, ww = x - j + 1;
          if (hh >= 0 && hh < HGT && ww >= 0 && ww < WID) docenter(i, j);
        }
    }
    float* o = &Wl[tid * 25];
    #pragma unroll
    for (int k = 0; k < 25; k++) o[k] = W[k];
  }
  __syncthreads();

  // ---- phase 2: apply 5x5 kernels (16 pixels x 16 ch-groups, 1 iter) ----
  const int pixL = tid >> 4;          // 0..15
  const int ch16 = tid & 15;
  const int y = y0 + (pixL >> 2), x = x0 + (pixL & 3);
  const size_t pixofs = (size_t)(bofs + y * WID + x);
  const int c0 = s * 128 + ch16 * 8;
  const float* Wp = &Wl[(pixL * 4 + (ch16 >> 2)) * 25];
  // top-left tap base honoring the transpose quirk: pixel (row=x-2, col=y-2);
  // tap (a,e) adds e*WID + a.
  const hbf16* vb0 = vprojb + (size_t)(bofs + (x - 2) * WID + (y - 2)) * NVAL;

  float acc[8];
  #pragma unroll
  for (int k = 0; k < 8; k++) acc[k] = 0.f;

  if (interior) {
    #pragma unroll
    for (int e = 0; e < 5; e++) {
      u32x4 t[5];
      #pragma unroll
      for (int a = 0; a < 5; a++)
        t[a] = *(const u32x4*)(vb0 + (e * WID + a) * NVAL + c0);
      #pragma unroll
      for (int a = 0; a < 5; a++) {
        const float w_ = Wp[a * 5 + e];
        acc[0] += w_ * __uint_as_float(t[a][0] << 16);
        acc[1] += w_ * __uint_as_float(t[a][0] & 0xffff0000u);
        acc[2] += w_ * __uint_as_float(t[a][1] << 16);
        acc[3] += w_ * __uint_as_float(t[a][1] & 0xffff0000u);
        acc[4] += w_ * __uint_as_float(t[a][2] << 16);
        acc[5] += w_ * __uint_as_float(t[a][2] & 0xffff0000u);
        acc[6] += w_ * __uint_as_float(t[a][3] << 16);
        acc[7] += w_ * __uint_as_float(t[a][3] & 0xffff0000u);
      }
    }
  } else {
    #pragma unroll
    for (int e = 0; e < 5; e++) {
      const int hi = x + e - 2;
      #pragma unroll
      for (int a = 0; a < 5; a++) {
        const int wi = y + a - 2;
        if (wi >= 0 && wi < WID && hi >= 0 && hi < HGT) {
          const float w_ = Wp[a * 5 + e];
          const u32x4 vv = *(const u32x4*)(
              vprojb + (size_t)(bofs + hi * WID + wi) * NVAL + c0);
          acc[0] += w_ * __uint_as_float(vv[0] << 16);
          acc[1] += w_ * __uint_as_float(vv[0] & 0xffff0000u);
          acc[2] += w_ * __uint_as_float(vv[1] << 16);
          acc[3] += w_ * __uint_as_float(vv[1] & 0xffff0000u);
          acc[4] += w_ * __uint_as_float(vv[2] << 16);
          acc[5] += w_ * __uint_as_float(vv[2] & 0xffff0000u);
          acc[6] += w_ * __uint_as_float(vv[3] << 16);
          acc[7] += w_ * __uint_as_float(vv[3] & 0xffff0000u);
        }
      }
    }
  }

  bf16x8 o;
  #pragma unroll
  for (int k = 0; k < 8; k++) o[k] = (__bf16)__float2bfloat16(acc[k]);
  *(bf16x8*)(foldedb + pixofs * NVAL + c0) = o;
}

// ---------------------------------------------------------------------------
extern "C" void kernel_launch(void* const* d_in, const int* in_sizes, int n_in,
                              void* d_out, int out_size, void* d_ws, size_t ws_size,
                              hipStream_t stream)
{
  const float* x  = (const float*)d_in[0];
  const float* Wv = (const float*)d_in[1];
  const float* Wa = (const float*)d_in[2];
  const float* ba = (const float*)d_in[3];
  const float* Wp = (const float*)d_in[4];
  const float* bp = (const float*)d_in[5];
  float* out = (float*)d_out;

  char* w = (char*)d_ws;
  const size_t ATTN_B  = (size_t)NPIX * NATT_W * 2;     // 57.8 MB
  const size_t VPROJ_B = (size_t)NPIX * NVAL * 2;       // 19.3 MB
  const size_t XB_B    = (size_t)NPIX * CIN * 2;        // 19.3 MB
  hbf16* attnb  = (hbf16*)w;
  hbf16* vprojb = (hbf16*)(w + ATTN_B);
  hbf16* xb     = (hbf16*)(w + ATTN_B + VPROJ_B);
  hbf16* wcat   = (hbf16*)(w + ATTN_B + VPROJ_B + XB_B);
  hbf16* wpb    = wcat + (size_t)NQKV * CIN;
  float* bcat   = (float*)(wpb + (size_t)CIN * CIN);
  hbf16* foldedb = xb;            // reuse: xb dead after the QKV GEMM

  // 1) all preprocessing in one kernel
  prep_all<<<dim3(NB_CONVX + NB_WQKV + NB_WP), 256, 0, stream>>>(
      x, Wv, Wa, ba, Wp, xb, wcat, bcat, wpb);
  // 2) fused V+A projection (XCD-grouped 1-D grid: 196 m-tiles x 12 n-tiles)
  gemm_fused<0><<<dim3(MB_TOT * (NQKV / 128)), 256, 0, stream>>>(
      xb, wcat, bcat, vprojb, attnb, nullptr);
  // 3) softmax + collapse + apply + fold (c-sliced) -> foldedb bf16
  fold_fused<<<dim3(8 * 196, 3), 256, 0, stream>>>(attnb, vprojb, foldedb);
  // 4) output projection (XCD-grouped: 196 x 3), transpose-out to [B,384,HW]
  gemm_fused<1><<<dim3(MB_TOT * (NVAL / 128)), 256, 0, stream>>>(
      foldedb, wpb, bp, nullptr, nullptr, out);
}